// Round 2
// baseline (654.999 us; speedup 1.0000x reference)
//
#include <hip/hip_runtime.h>

typedef __attribute__((ext_vector_type(4))) float f32x4;
typedef __attribute__((ext_vector_type(8))) short bf16x8;
typedef __attribute__((ext_vector_type(4))) unsigned short u16x4;
typedef __attribute__((ext_vector_type(8))) unsigned short u16x8;

#define NB 4096
#define NS 6
#define NC 2048
#define ND 256
#define MTOT (NB * NS)   // 24576

static __device__ __forceinline__ unsigned short f2bf(float f) {
  unsigned u = __float_as_uint(f);
  u += 0x7FFFu + ((u >> 16) & 1u);   // round-to-nearest-even
  return (unsigned short)(u >> 16);
}
static __device__ __forceinline__ float bf2f(unsigned short h) {
  return __uint_as_float(((unsigned)h) << 16);
}

// ---------------- prep: x (fp32) -> x_hi + x_lo (bf16) ----------------
__global__ void split_x_kernel(const float* __restrict__ x,
                               unsigned short* __restrict__ hi,
                               unsigned short* __restrict__ lo, int n4) {
  int i = blockIdx.x * blockDim.x + threadIdx.x;
  const int stride = gridDim.x * blockDim.x;
  for (; i < n4; i += stride) {
    f32x4 v = reinterpret_cast<const f32x4*>(x)[i];
    u16x4 h, l;
#pragma unroll
    for (int j = 0; j < 4; ++j) {
      unsigned short hb = f2bf(v[j]);
      h[j] = hb;
      l[j] = f2bf(v[j] - bf2f(hb));
    }
    reinterpret_cast<u16x4*>(hi)[i] = h;
    reinterpret_cast<u16x4*>(lo)[i] = l;
  }
}

// ------------- prep: [Wq;Wk] stacked -> hi/lo (bf16), 512 x 2048 -------------
__global__ void prep_wqk_kernel(const float* __restrict__ Wq,
                                const float* __restrict__ Wk,
                                unsigned short* __restrict__ hi,
                                unsigned short* __restrict__ lo) {
  int i = blockIdx.x * blockDim.x + threadIdx.x;  // over 512*2048/4 = 262144 float4
  const int stride = gridDim.x * blockDim.x;
  for (; i < 262144; i += stride) {
    const int row = i >> 9;         // 512 float4 per row
    const int col4 = i & 511;
    const float* src = (row < 256) ? (Wq + (size_t)row * NC)
                                   : (Wk + (size_t)(row - 256) * NC);
    f32x4 v = reinterpret_cast<const f32x4*>(src)[col4];
    u16x4 h, l;
#pragma unroll
    for (int j = 0; j < 4; ++j) {
      unsigned short hb = f2bf(v[j]);
      h[j] = hb;
      l[j] = f2bf(v[j] - bf2f(hb));
    }
    reinterpret_cast<u16x4*>(hi)[i] = h;
    reinterpret_cast<u16x4*>(lo)[i] = l;
  }
}

// ---------------- prep: Wv -> bf16 ----------------
__global__ void conv_bf16_kernel(const float* __restrict__ in,
                                 unsigned short* __restrict__ out, int n4) {
  int i = blockIdx.x * blockDim.x + threadIdx.x;
  const int stride = gridDim.x * blockDim.x;
  for (; i < n4; i += stride) {
    f32x4 v = reinterpret_cast<const f32x4*>(in)[i];
    u16x4 o;
#pragma unroll
    for (int j = 0; j < 4; ++j) o[j] = f2bf(v[j]);
    reinterpret_cast<u16x4*>(out)[i] = o;
  }
}

// ---------------- GEMM: C[M,N] = sum_seg A_seg[M,K] * B_seg[N,K]^T ----------------
// m97-style: 128x128 tile, BK=32, 4 waves (2x2), 16x16x32 bf16 MFMA,
// global_load_lds width 16, linear LDS. Optional epilogue: C = gamma*acc + resid.
template <int NSEG, bool EPI>
__global__ void __launch_bounds__(256, 2)
gemm_bt(const unsigned short* __restrict__ A0, const unsigned short* __restrict__ B0,
        const unsigned short* __restrict__ A1, const unsigned short* __restrict__ B1,
        const unsigned short* __restrict__ A2, const unsigned short* __restrict__ B2,
        const int N, const int K, float* __restrict__ C,
        const float* __restrict__ resid, const float* __restrict__ gam) {
  __shared__ unsigned short lA[128 * 32];
  __shared__ unsigned short lB[128 * 32];
  const int t = threadIdx.x;
  const int lane = t & 63;
  const int wv = t >> 6;
  const int wr = wv >> 1, wc = wv & 1;
  const int m0 = blockIdx.y * 128;
  const int n0 = blockIdx.x * 128;

  f32x4 acc[4][4] = {};

  const unsigned short* As[3] = {A0, A1, A2};
  const unsigned short* Bs[3] = {B0, B1, B2};

  const int trow = t >> 2;        // 0..63 (row within 64-row staging chunk)
  const int tcol = (t & 3) * 8;   // k-offset (8 bf16 = 16B per lane)
  const unsigned ldsWave = (unsigned)(t >> 6) * 1024u;  // wave-uniform LDS base
  const int fr = lane & 15;
  const int fk = (lane >> 4) * 8;

#pragma unroll
  for (int seg = 0; seg < NSEG; ++seg) {
    const unsigned short* Aseg = As[seg];
    const unsigned short* Bseg = Bs[seg];
    for (int k0 = 0; k0 < K; k0 += 32) {
      __syncthreads();
#pragma unroll
      for (int ch = 0; ch < 2; ++ch) {
        const unsigned short* ga =
            Aseg + (size_t)(m0 + ch * 64 + trow) * (size_t)K + (k0 + tcol);
        const unsigned short* gb =
            Bseg + (size_t)(n0 + ch * 64 + trow) * (size_t)K + (k0 + tcol);
        __builtin_amdgcn_global_load_lds(
            (__attribute__((address_space(1))) void*)ga,
            (__attribute__((address_space(3))) void*)(((char*)lA) + ch * 4096 + ldsWave),
            16, 0, 0);
        __builtin_amdgcn_global_load_lds(
            (__attribute__((address_space(1))) void*)gb,
            (__attribute__((address_space(3))) void*)(((char*)lB) + ch * 4096 + ldsWave),
            16, 0, 0);
      }
      __syncthreads();
      bf16x8 af[4], bg[4];
#pragma unroll
      for (int m = 0; m < 4; ++m)
        af[m] = *reinterpret_cast<const bf16x8*>(&lA[(wr * 64 + m * 16 + fr) * 32 + fk]);
#pragma unroll
      for (int n = 0; n < 4; ++n)
        bg[n] = *reinterpret_cast<const bf16x8*>(&lB[(wc * 64 + n * 16 + fr) * 32 + fk]);
#pragma unroll
      for (int m = 0; m < 4; ++m)
#pragma unroll
        for (int n = 0; n < 4; ++n)
          acc[m][n] = __builtin_amdgcn_mfma_f32_16x16x32_bf16(af[m], bg[n], acc[m][n], 0, 0, 0);
    }
  }

  // epilogue: C/D layout col = lane&15, row = (lane>>4)*4 + j  [m89-verified]
  float g = 0.f;
  if (EPI) g = gam[0];
#pragma unroll
  for (int m = 0; m < 4; ++m)
#pragma unroll
    for (int n = 0; n < 4; ++n)
#pragma unroll
      for (int j = 0; j < 4; ++j) {
        const int r = m0 + wr * 64 + m * 16 + (lane >> 4) * 4 + j;
        const int c = n0 + wc * 64 + n * 16 + (lane & 15);
        const size_t idx = (size_t)r * (size_t)N + (size_t)c;
        float v = acc[m][n][j];
        if (EPI) v = g * v + resid[idx];
        C[idx] = v;
      }
}

// ---------------- per-batch: energy (fp32) -> softmax -> attn out + y = attn@x ----------------
__global__ void __launch_bounds__(256)
attn_fuse(const float* __restrict__ QK,   // [MTOT, 512] : cols 0..255 = q, 256..511 = k
          const float* __restrict__ x,    // [MTOT, 2048] fp32
          float* __restrict__ attn_out,   // [NB, 36] fp32
          unsigned short* __restrict__ y) // [MTOT, 2048] bf16
{
  __shared__ float qk[NS * 512];
  __shared__ float eng[36];
  __shared__ float att[36];
  const int b = blockIdx.x;
  const int t = threadIdx.x;
  {
    const f32x4* src = reinterpret_cast<const f32x4*>(QK + (size_t)b * (NS * 512));
    f32x4* dst = reinterpret_cast<f32x4*>(qk);
    for (int i = t; i < (NS * 512) / 4; i += 256) dst[i] = src[i];
  }
  __syncthreads();
  // energies: 36 (s,u) pairs x 4 lanes each over 64 elements
  if (t < 144) {
    const int s = t / 24;
    const int rem = t - s * 24;
    const int u = rem >> 2;
    const int sub = rem & 3;
    const float* qr = qk + s * 512;
    const float* kr = qk + u * 512 + 256;
    float sum = 0.f;
    const int d0 = sub * 64;
#pragma unroll 4
    for (int d = 0; d < 64; ++d) sum += qr[d0 + d] * kr[d0 + d];
    sum += __shfl_xor(sum, 1);
    sum += __shfl_xor(sum, 2);
    if (sub == 0) eng[s * 6 + u] = sum;
  }
  __syncthreads();
  if (t < 6) {
    float e[6];
#pragma unroll
    for (int u = 0; u < 6; ++u) e[u] = eng[t * 6 + u];
    float mx = e[0];
#pragma unroll
    for (int u = 1; u < 6; ++u) mx = fmaxf(mx, e[u]);
    float p[6];
    float sm = 0.f;
#pragma unroll
    for (int u = 0; u < 6; ++u) { p[u] = expf(e[u] - mx); sm += p[u]; }
    const float inv = 1.0f / sm;
#pragma unroll
    for (int u = 0; u < 6; ++u) {
      const float a = p[u] * inv;
      att[t * 6 + u] = a;
      attn_out[(size_t)b * 36 + t * 6 + u] = a;
    }
  }
  __syncthreads();
  // y[s, c] = sum_u att[s][u] * x[u, c]  (8 columns per thread)
  const float* xb = x + (size_t)b * (NS * NC);
  unsigned short* yb = y + (size_t)b * (NS * NC);
  const int c0 = t * 8;
  f32x4 xv[12];
#pragma unroll
  for (int u = 0; u < 6; ++u) {
    xv[2 * u]     = *reinterpret_cast<const f32x4*>(xb + u * NC + c0);
    xv[2 * u + 1] = *reinterpret_cast<const f32x4*>(xb + u * NC + c0 + 4);
  }
#pragma unroll
  for (int s = 0; s < 6; ++s) {
    f32x4 a0 = 0.f, a1 = 0.f;
#pragma unroll
    for (int u = 0; u < 6; ++u) {
      const float w = att[s * 6 + u];
      a0 += w * xv[2 * u];
      a1 += w * xv[2 * u + 1];
    }
    u16x8 o;
#pragma unroll
    for (int j = 0; j < 4; ++j) { o[j] = f2bf(a0[j]); o[4 + j] = f2bf(a1[j]); }
    *reinterpret_cast<u16x8*>(yb + s * NC + c0) = o;
  }
}

extern "C" void kernel_launch(void* const* d_in, const int* in_sizes, int n_in,
                              void* d_out, int out_size, void* d_ws, size_t ws_size,
                              hipStream_t stream) {
  (void)in_sizes; (void)n_in; (void)out_size; (void)ws_size;
  const float* x   = (const float*)d_in[0];
  const float* Wq  = (const float*)d_in[1];
  const float* Wk  = (const float*)d_in[2];
  const float* Wv  = (const float*)d_in[3];
  const float* gam = (const float*)d_in[4];
  float* out = (float*)d_out;
  float* attn_out = out + (size_t)MTOT * NC;   // second output, [NB,6,6]

  // workspace layout (bytes):
  char* ws = (char*)d_ws;
  unsigned short* xh   = (unsigned short*)(ws);                    // 100663296
  unsigned short* xl   = (unsigned short*)(ws + 100663296ull);     // 100663296 (reused as y)
  unsigned short* wqkh = (unsigned short*)(ws + 201326592ull);     // 2097152
  unsigned short* wqkl = (unsigned short*)(ws + 203423744ull);     // 2097152
  unsigned short* wvb  = (unsigned short*)(ws + 205520896ull);     // 8388608
  float*          qkb  = (float*)(ws + 213909504ull);              // 50331648 -> total 264241152

  split_x_kernel<<<2048, 256, 0, stream>>>(x, xh, xl, MTOT * NC / 4);
  prep_wqk_kernel<<<256, 256, 0, stream>>>(Wq, Wk, wqkh, wqkl);
  conv_bf16_kernel<<<512, 256, 0, stream>>>(Wv, wvb, NC * NC / 4);

  // QK = x @ [Wq;Wk]^T  with 3-pass hi/lo split for fp32-grade accuracy
  gemm_bt<3, false><<<dim3(4, 192), 256, 0, stream>>>(
      xh, wqkh, xh, wqkl, xl, wqkh, 512, NC, qkb, nullptr, nullptr);

  // energies + softmax + attention output + y = attn @ x   (y overwrites xl)
  attn_fuse<<<NB, 256, 0, stream>>>(qkb, x, attn_out, xl);

  // out = gamma * (y @ Wv^T) + x
  gemm_bt<1, true><<<dim3(16, 192), 256, 0, stream>>>(
      xl, wvb, nullptr, nullptr, nullptr, nullptr, NC, NC, out, x, gam);
}

// Round 4
// 558.436 us; speedup vs baseline: 1.1729x; 1.1729x over previous
//
#include <hip/hip_runtime.h>

typedef __attribute__((ext_vector_type(4))) float f32x4;
typedef __attribute__((ext_vector_type(8))) short bf16x8;
typedef __attribute__((ext_vector_type(4))) unsigned short u16x4;
typedef __attribute__((ext_vector_type(8))) unsigned short u16x8;

#define NB 4096
#define NS 6
#define NC 2048
#define MTOT (NB * NS)   // 24576

static __device__ __forceinline__ unsigned short f2bf(float f) {
  unsigned u = __float_as_uint(f);
  u += 0x7FFFu + ((u >> 16) & 1u);
  return (unsigned short)(u >> 16);
}
static __device__ __forceinline__ float bf2f(unsigned short h) {
  return __uint_as_float(((unsigned)h) << 16);
}

// ---------------- prep kernels ----------------
__global__ void split_x_kernel(const float* __restrict__ x,
                               unsigned short* __restrict__ hi,
                               unsigned short* __restrict__ lo, int n4) {
  int i = blockIdx.x * blockDim.x + threadIdx.x;
  const int stride = gridDim.x * blockDim.x;
  for (; i < n4; i += stride) {
    f32x4 v = reinterpret_cast<const f32x4*>(x)[i];
    u16x4 h, l;
#pragma unroll
    for (int j = 0; j < 4; ++j) {
      unsigned short hb = f2bf(v[j]);
      h[j] = hb;
      l[j] = f2bf(v[j] - bf2f(hb));
    }
    reinterpret_cast<u16x4*>(hi)[i] = h;
    reinterpret_cast<u16x4*>(lo)[i] = l;
  }
}

__global__ void prep_wqk_kernel(const float* __restrict__ Wq,
                                const float* __restrict__ Wk,
                                unsigned short* __restrict__ hi,
                                unsigned short* __restrict__ lo) {
  int i = blockIdx.x * blockDim.x + threadIdx.x;
  const int stride = gridDim.x * blockDim.x;
  for (; i < 262144; i += stride) {
    const int row = i >> 9;
    const int col4 = i & 511;
    const float* src = (row < 256) ? (Wq + (size_t)row * NC)
                                   : (Wk + (size_t)(row - 256) * NC);
    f32x4 v = reinterpret_cast<const f32x4*>(src)[col4];
    u16x4 h, l;
#pragma unroll
    for (int j = 0; j < 4; ++j) {
      unsigned short hb = f2bf(v[j]);
      h[j] = hb;
      l[j] = f2bf(v[j] - bf2f(hb));
    }
    reinterpret_cast<u16x4*>(hi)[i] = h;
    reinterpret_cast<u16x4*>(lo)[i] = l;
  }
}

__global__ void conv_bf16_kernel(const float* __restrict__ in,
                                 unsigned short* __restrict__ out, int n4) {
  int i = blockIdx.x * blockDim.x + threadIdx.x;
  const int stride = gridDim.x * blockDim.x;
  for (; i < n4; i += stride) {
    f32x4 v = reinterpret_cast<const f32x4*>(in)[i];
    u16x4 o;
#pragma unroll
    for (int j = 0; j < 4; ++j) o[j] = f2bf(v[j]);
    reinterpret_cast<u16x4*>(out)[i] = o;
  }
}

// ---------------- 256x256 8-phase GEMM ----------------
// C[M,N] = sum_seg A_seg[M,2048] * B_seg[N,2048]^T ; A/B bf16, C fp32.
// LDS: 2 buf x (A 32KB + B 32KB) = 128KB. Subtiled layout: each 1KB subtile
// = 16 rows x 32 cols bf16 (one MFMA fragment) -> conflict-free ds_read_b128
// and lane-linear global_load_lds chunks. Raw s_barrier + counted vmcnt(4).
// Staging WRAPS past NT (tile index mod NT) so the per-wave outstanding-load
// count is exact at every tile; wrapped loads land in regions whose readable
// data is never consumed again (tail-race fix vs round 3).

#define FENCE() asm volatile("" ::: "memory")
#define BAR() do { FENCE(); __builtin_amdgcn_s_barrier(); FENCE(); } while (0)
#define VM4BAR() do { FENCE(); asm volatile("s_waitcnt vmcnt(4)" ::: "memory"); \
                      __builtin_amdgcn_s_barrier(); FENCE(); } while (0)

template <int MB>
__device__ __forceinline__ void mfma_blk(f32x4 (&acc)[8][4], const bf16x8 (&Av)[4],
                                         const bf16x8 (&Bv)[4]) {
  __builtin_amdgcn_s_setprio(1);
#pragma unroll
  for (int m = 0; m < 4; ++m)
#pragma unroll
    for (int n = 0; n < 4; ++n)
      acc[MB + m][n] =
          __builtin_amdgcn_mfma_f32_16x16x32_bf16(Av[m], Bv[n], acc[MB + m][n], 0, 0, 0);
  __builtin_amdgcn_s_setprio(0);
}

__device__ __forceinline__ void load4(bf16x8 (&dst)[4], const char* base, int kk) {
#pragma unroll
  for (int m = 0; m < 4; ++m)
    dst[m] = *reinterpret_cast<const bf16x8*>(base + (m * 2 + kk) * 1024);
}

__device__ __forceinline__ void stage_op(const unsigned short* g, int row0, int k0,
                                         char* ldsOp, int wid, int lane) {
#pragma unroll
  for (int h = 0; h < 2; ++h)
#pragma unroll
    for (int i = 0; i < 2; ++i) {
      const int c = wid * 2 + i;
      const unsigned short* src =
          g + (size_t)(row0 + h * 128 + (c >> 1) * 16 + (lane >> 2)) * 2048 +
          (unsigned)(k0 + (c & 1) * 32 + (lane & 3) * 8);
      __builtin_amdgcn_global_load_lds(
          (__attribute__((address_space(1))) void*)src,
          (__attribute__((address_space(3))) void*)(ldsOp + h * 16384 + c * 1024),
          16, 0, 0);
    }
}

template <int NSEG, int N, bool EPI>
__global__ void __launch_bounds__(512, 2)
gemm256(const unsigned short* __restrict__ A0, const unsigned short* __restrict__ B0,
        const unsigned short* __restrict__ A1, const unsigned short* __restrict__ B1,
        const unsigned short* __restrict__ A2, const unsigned short* __restrict__ B2,
        float* __restrict__ C, const float* __restrict__ resid,
        const float* __restrict__ gam) {
  constexpr int NTPS = 2048 / 64;       // K-tiles per segment (32)
  constexpr int NT = NSEG * NTPS;       // total K-tiles (even)
  constexpr int MT = MTOT / 256;        // 96
  constexpr int NXT = N / 256;
  constexpr int NWG = MT * NXT;
  constexpr int CPX = NWG / 8;
  __shared__ char lds[131072];

  const int bid = blockIdx.x;
  const int wg = (bid & 7) * CPX + (bid >> 3);   // XCD swizzle (NWG%8==0)
  const int bx = wg / MT;
  const int by = wg % MT;
  const int m0 = by * 256, n0 = bx * 256;

  const int t = threadIdx.x;
  const int lane = t & 63;
  const int wid = t >> 6;
  const int wr = wid >> 2, wc = wid & 3;
  const int laneOff = (lane & 15) * 64 + (lane >> 4) * 16;

  f32x4 acc[8][4] = {};
  bf16x8 A03[4], A47[4], Bk0[4], Bk1[4];

  const int aBase = wr * 16384 + laneOff;
  const int bBase = 32768 + (wc >> 1) * 16384 + (wc & 1) * 8192 + laneOff;

#define SEL(P0, P1, P2, S) ((NSEG == 1) ? (P0) : ((S) == 0 ? (P0) : ((S) == 1 ? (P1) : (P2))))
#define WRAPT(TT) ((TT) >= NT ? (TT) - NT : (TT))
#define STAGE_A(TT) do { int tw_ = WRAPT(TT); int s_ = tw_ / NTPS; \
    stage_op(SEL(A0, A1, A2, s_), m0, (tw_ % NTPS) * 64, lds + ((TT) & 1) * 65536, wid, lane); } while (0)
#define STAGE_B(TT) do { int tw_ = WRAPT(TT); int s_ = tw_ / NTPS; \
    stage_op(SEL(B0, B1, B2, s_), n0, (tw_ % NTPS) * 64, lds + ((TT) & 1) * 65536 + 32768, wid, lane); } while (0)

  // prologue: tile0 A+B, tile1 B; drain tile0, leave tile1-B in flight
  STAGE_A(0);
  STAGE_B(0);
  STAGE_B(1);
  VM4BAR();

#define TILE(TAU, FIRST) do { \
    char* bufc = lds + ((TAU) & 1) * 65536; \
    /* p0 */ \
    load4(A03, bufc + aBase, 0); \
    load4(Bk0, bufc + bBase, 0); \
    STAGE_A((TAU) + 1); \
    BAR(); \
    if (!(FIRST)) mfma_blk<4>(acc, A47, Bk1); \
    BAR(); \
    /* p1 */ \
    load4(A47, bufc + aBase + 8192, 0); \
    BAR(); \
    mfma_blk<0>(acc, A03, Bk0); \
    BAR(); \
    /* p2 */ \
    load4(A03, bufc + aBase, 1); \
    load4(Bk1, bufc + bBase, 1); \
    BAR(); \
    mfma_blk<4>(acc, A47, Bk0); \
    BAR(); \
    /* p3 */ \
    load4(A47, bufc + aBase + 8192, 1); \
    STAGE_B((TAU) + 2); \
    VM4BAR(); \
    mfma_blk<0>(acc, A03, Bk1); \
    BAR(); \
  } while (0)

  TILE(0, 1);
  for (int tau = 1; tau < NT; ++tau) TILE(tau, 0);
  mfma_blk<4>(acc, A47, Bk1);   // trailing quadrant of last tile

#undef TILE
#undef STAGE_A
#undef STAGE_B
#undef WRAPT
#undef SEL

  // epilogue: C/D layout col = lane&15, row = (lane>>4)*4 + j
  const float g = EPI ? gam[0] : 0.f;
#pragma unroll
  for (int m = 0; m < 8; ++m)
#pragma unroll
    for (int n = 0; n < 4; ++n)
#pragma unroll
      for (int j = 0; j < 4; ++j) {
        const int r = m0 + wr * 128 + m * 16 + (lane >> 4) * 4 + j;
        const int c = n0 + wc * 64 + n * 16 + (lane & 15);
        const size_t idx = (size_t)r * (size_t)N + (size_t)c;
        float v = acc[m][n][j];
        if (EPI) v = g * v + resid[idx];
        C[idx] = v;
      }
}

// ---------------- per-batch: energy -> softmax -> attn out + y = attn@x ----------------
__global__ void __launch_bounds__(256)
attn_fuse(const float* __restrict__ QK,          // [MTOT, 512] cols 0..255=q, 256..511=k
          const unsigned short* __restrict__ xh, // [MTOT, 2048] bf16
          float* __restrict__ attn_out,          // [NB, 36]
          unsigned short* __restrict__ y)        // [MTOT, 2048] bf16
{
  __shared__ float qk[NS * 512];
  __shared__ float eng[36];
  __shared__ float att[36];
  const int b = blockIdx.x;
  const int t = threadIdx.x;
  {
    const f32x4* src = reinterpret_cast<const f32x4*>(QK + (size_t)b * (NS * 512));
    f32x4* dst = reinterpret_cast<f32x4*>(qk);
    for (int i = t; i < (NS * 512) / 4; i += 256) dst[i] = src[i];
  }
  __syncthreads();
  if (t < 144) {
    const int s = t / 24;
    const int rem = t - s * 24;
    const int u = rem >> 2;
    const int sub = rem & 3;
    const float* qr = qk + s * 512;
    const float* kr = qk + u * 512 + 256;
    float sum = 0.f;
    const int d0 = sub * 64;
#pragma unroll 4
    for (int d = 0; d < 64; ++d) sum += qr[d0 + d] * kr[d0 + d];
    sum += __shfl_xor(sum, 1);
    sum += __shfl_xor(sum, 2);
    if (sub == 0) eng[s * 6 + u] = sum;
  }
  __syncthreads();
  if (t < 6) {
    float e[6];
#pragma unroll
    for (int u = 0; u < 6; ++u) e[u] = eng[t * 6 + u];
    float mx = e[0];
#pragma unroll
    for (int u = 1; u < 6; ++u) mx = fmaxf(mx, e[u]);
    float p[6];
    float sm = 0.f;
#pragma unroll
    for (int u = 0; u < 6; ++u) { p[u] = expf(e[u] - mx); sm += p[u]; }
    const float inv = 1.0f / sm;
#pragma unroll
    for (int u = 0; u < 6; ++u) {
      const float a = p[u] * inv;
      att[t * 6 + u] = a;
      attn_out[(size_t)b * 36 + t * 6 + u] = a;
    }
  }
  __syncthreads();
  const unsigned short* xb = xh + (size_t)b * (NS * NC);
  unsigned short* yb = y + (size_t)b * (NS * NC);
  const int c0 = t * 8;
  f32x4 xv[12];
#pragma unroll
  for (int u = 0; u < 6; ++u) {
    u16x8 v = *reinterpret_cast<const u16x8*>(xb + u * NC + c0);
#pragma unroll
    for (int j = 0; j < 4; ++j) {
      xv[2 * u][j] = bf2f(v[j]);
      xv[2 * u + 1][j] = bf2f(v[4 + j]);
    }
  }
#pragma unroll
  for (int s = 0; s < 6; ++s) {
    f32x4 a0 = 0.f, a1 = 0.f;
#pragma unroll
    for (int u = 0; u < 6; ++u) {
      const float w = att[s * 6 + u];
      a0 += w * xv[2 * u];
      a1 += w * xv[2 * u + 1];
    }
    u16x8 o;
#pragma unroll
    for (int j = 0; j < 4; ++j) { o[j] = f2bf(a0[j]); o[4 + j] = f2bf(a1[j]); }
    *reinterpret_cast<u16x8*>(yb + s * NC + c0) = o;
  }
}

extern "C" void kernel_launch(void* const* d_in, const int* in_sizes, int n_in,
                              void* d_out, int out_size, void* d_ws, size_t ws_size,
                              hipStream_t stream) {
  (void)in_sizes; (void)n_in; (void)out_size; (void)ws_size;
  const float* x   = (const float*)d_in[0];
  const float* Wq  = (const float*)d_in[1];
  const float* Wk  = (const float*)d_in[2];
  const float* Wv  = (const float*)d_in[3];
  const float* gam = (const float*)d_in[4];
  float* out = (float*)d_out;
  float* attn_out = out + (size_t)MTOT * NC;

  char* ws = (char*)d_ws;
  unsigned short* xh   = (unsigned short*)(ws);                    // 100663296 B
  unsigned short* xl   = (unsigned short*)(ws + 100663296ull);     // 100663296 B (reused as y)
  unsigned short* wqkh = (unsigned short*)(ws + 201326592ull);     // 2097152 B
  unsigned short* wqkl = (unsigned short*)(ws + 203423744ull);     // 2097152 B
  unsigned short* wvb  = (unsigned short*)(ws + 205520896ull);     // 8388608 B
  float*          qkb  = (float*)(ws + 213909504ull);              // 50331648 B

  split_x_kernel<<<2048, 256, 0, stream>>>(x, xh, xl, MTOT * NC / 4);
  prep_wqk_kernel<<<256, 256, 0, stream>>>(Wq, Wk, wqkh, wqkl);
  conv_bf16_kernel<<<512, 256, 0, stream>>>(Wv, wvb, NC * NC / 4);

  // QK = x @ [Wq;Wk]^T, 3-pass hi/lo split (x_hi*W_hi + x_hi*W_lo + x_lo*W_hi)
  gemm256<3, 512, false><<<192, 512, 0, stream>>>(
      xh, wqkh, xh, wqkl, xl, wqkh, qkb, nullptr, nullptr);

  // energies + softmax + attention output + y = attn @ x (y overwrites xl)
  attn_fuse<<<NB, 256, 0, stream>>>(qkb, xh, attn_out, xl);

  // out = gamma * (y @ Wv^T) + x
  gemm256<1, 2048, true><<<768, 512, 0, stream>>>(
      xl, wvb, nullptr, nullptr, nullptr, nullptr, out, x, gam);
}